// Round 4
// baseline (2962.208 us; speedup 1.0000x reference)
//
#include <hip/hip_runtime.h>

#define NSEQ 1028
#define TT   256
#define CC   64
#define HH   256
#define AROWB 656                              // bytes per A row: 320*2 + 16 (stride ≡16 mod 128 → conflict-free b128)
#define HSLAB 16384                            // elems per (side,kt) half-slab: 8w*4ct*512
#define LSTM_LDS (2*16*AROWB + 2*2*HSLAB)      // 20992 + 65536 = 86528
#define OUTP_LDS (128*264*2 + 64*264*2)        // 101376

typedef unsigned short u16;
typedef float  f32x4 __attribute__((ext_vector_type(4)));
typedef __bf16 v8bf  __attribute__((ext_vector_type(8)));

__device__ __forceinline__ u16 f2bf(float f){
  unsigned u = __builtin_bit_cast(unsigned, f);
  u += 0x7FFFu + ((u >> 16) & 1u);
  return (u16)(u >> 16);
}
__device__ __forceinline__ float sigm(float x){
  float t = __builtin_amdgcn_exp2f(-1.4426950408889634f * x);
  return __builtin_amdgcn_rcpf(1.0f + t);
}
__device__ __forceinline__ float tanh_f(float x){
  float a = __builtin_fabsf(x);
  float t = __builtin_amdgcn_exp2f(-2.885390081777927f * a);
  float r = (1.0f - t) * __builtin_amdgcn_rcpf(1.0f + t);
  return __builtin_copysignf(r, x);
}
// MFMA with B pinned in AGPR (forces weight residency in accumulator file)
__device__ __forceinline__ void mfma_a(f32x4& d, v8bf a, v8bf b){
  asm("v_mfma_f32_16x16x32_bf16 %0, %1, %2, %0" : "+v"(d) : "v"(a), "a"(b));
}
__device__ __forceinline__ void mfma_v(f32x4& d, v8bf a, v8bf b){
  asm("v_mfma_f32_16x16x32_bf16 %0, %1, %2, %0" : "+v"(d) : "v"(a), "v"(b));
}

// ---- pack W into gate-split per-(side,kt,wave,ct) MFMA B-frags, bf16
// block-col c = ct*128 + w*16 + l15 -> global W row = ct*256 + s*128 + w*16 + l15
__global__ void k_pack_w(const float* __restrict__ Whh, const float* __restrict__ Wih,
                         u16* __restrict__ wpack){
  int idx = blockIdx.x*256 + threadIdx.x;
  if (idx >= 2*10*HSLAB) return;                // 327680
  int j    = idx & 7;
  int lane = (idx >> 3) & 63;
  int ct   = (idx >> 9) & 3;
  int w    = (idx >> 11) & 7;
  int rem  = idx >> 14;
  int kt   = rem % 10, s = rem / 10;
  int row  = ct*256 + s*128 + w*16 + (lane & 15);
  int k    = kt*32 + (lane >> 4)*8 + j;
  float v  = (k < 256) ? Whh[row*256 + k] : Wih[row*64 + (k - 256)];
  wpack[idx] = f2bf(v);
}

__global__ void k_bias(const float* __restrict__ bi, const float* __restrict__ bh,
                       float* __restrict__ bias){
  int i = blockIdx.x*256 + threadIdx.x;
  if (i < 1024) bias[i] = bi[i] + bh[i];
}

__global__ void k_wlin(const float* __restrict__ Wl, u16* __restrict__ wlin){
  int i = blockIdx.x*256 + threadIdx.x;
  if (i >= 64*264) return;
  int col = i / 264, k = i % 264;
  wlin[i] = (k < 256) ? f2bf(Wl[col*256 + k]) : (u16)0;
}

// ---- x(B,C,F,T) -> y(n,t,c) bf16, n = b*257+f
__global__ void k_ytrans(const float* __restrict__ x, u16* __restrict__ ybuf){
  __shared__ u16 tile[64][257];
  int n = blockIdx.x, b = n / 257, f = n % 257, tid = threadIdx.x;
  for (int i = tid; i < 64*256; i += 256){
    int c = i >> 8, t = i & 255;
    tile[c][t] = f2bf(x[((size_t)(b*64 + c)*257 + f)*256 + t]);
  }
  __syncthreads();
  for (int i = tid; i < 256*64; i += 256){
    int t = i >> 6, c = i & 63;
    ybuf[((size_t)n*256 + t)*64 + c] = tile[c][t];
  }
}

// ---- persistent gate-split LSTM: pair p = blocks {bx, bx+8}, side s = unit half
// Weights fully resident: kt0..7 AGPR (128/wave), kt8,9 (x-part) in LDS. No streaming.
// Per-step h-half exchange through hbuf (t-indexed, no reuse) + monotonic flags.
__global__ __launch_bounds__(512, 2) void k_lstm(const u16* __restrict__ wpack,
      const float* __restrict__ bias, const u16* __restrict__ ybuf,
      u16* __restrict__ hbuf, int* __restrict__ flg){
  const int bx = blockIdx.x;
  const int s = (bx >> 3) & 1;
  const int p = (bx & 7) + 8*(bx >> 4);
  if (p >= 65) return;                          // 130 active of 144
  extern __shared__ char smem[];
  char* lA = smem;                              // [2][16 rows][AROWB]
  u16*  lW = (u16*)(smem + 2*16*AROWB);         // kt8,9 half-slabs
  const int tid = threadIdx.x, lane = tid & 63, w = tid >> 6;
  const int n0 = p * 16;
  const int l15 = lane & 15, q = lane >> 4;
  const int srow = tid >> 5, schunk = tid & 31; // staging roles: 16 rows x 32 chunks
  const int unit = w*16 + l15;                  // local unit within half

  const u16* wbase = wpack + (size_t)s * (10*HSLAB);

  // AGPR-resident W (kt0..7): 128 AGPR/wave, pinned by "a"-constrained MFMA uses
  v8bf wreg[8][4];
  #pragma unroll
  for (int kt = 0; kt < 8; ++kt)
    #pragma unroll
    for (int ct = 0; ct < 4; ++ct)
      wreg[kt][ct] = *(const v8bf*)(wbase + ((kt*8 + w)*4 + ct)*512 + lane*8);

  { // LDS-resident W (kt8,9)
    const uint4* src = (const uint4*)(wbase + 8*HSLAB);
    uint4* dst = (uint4*)lW;
    for (int i = tid; i < (2*HSLAB)/8; i += 512) dst[i] = src[i];
  }
  float biasr[4];
  #pragma unroll
  for (int ct = 0; ct < 4; ++ct) biasr[ct] = bias[ct*256 + s*128 + unit];

  { // zero both A buffers (h(-1)=0)
    unsigned* z = (unsigned*)lA;
    for (int i = tid; i < (2*16*AROWB)/4; i += 512) z[i] = 0;
  }
  __syncthreads();
  { // stage y[t=0] into buf0
    unsigned v = 0;
    if (n0 + srow < NSEQ)
      v = *(const unsigned*)(ybuf + ((size_t)(n0 + srow)*TT + 0)*64 + schunk*2);
    *(unsigned*)(lA + srow*AROWB + 512 + schunk*4) = v;
  }
  f32x4 creg = (f32x4){0.f, 0.f, 0.f, 0.f};
  __syncthreads();

  int* myflag = flg + (p*2 + s)*32;
  int* otflag = flg + (p*2 + (s^1))*32;

  for (int t = 0; t < TT; ++t){
    char* Acur = lA + (t & 1)*16*AROWB;
    char* Anxt = lA + ((t + 1) & 1)*16*AROWB;

    // y prefetch for t+1
    unsigned yv = 0;
    if (t + 1 < TT && n0 + srow < NSEQ)
      yv = *(const unsigned*)(ybuf + ((size_t)(n0 + srow)*TT + (t + 1))*64 + schunk*2);

    f32x4 acc[4];
    #pragma unroll
    for (int ct = 0; ct < 4; ++ct)
      acc[ct] = (f32x4){biasr[ct], biasr[ct], biasr[ct], biasr[ct]};
    asm volatile("s_nop 1"
      : "+v"(acc[0]), "+v"(acc[1]), "+v"(acc[2]), "+v"(acc[3]));

    #define AFRAG(kt) (*(const v8bf*)(Acur + l15*AROWB + (kt)*64 + q*16))

    #pragma unroll
    for (int kt = 0; kt < 8; ++kt){
      v8bf a = AFRAG(kt);
      #pragma unroll
      for (int ct = 0; ct < 4; ++ct) mfma_a(acc[ct], a, wreg[kt][ct]);
    }
    #pragma unroll
    for (int kt = 8; kt < 10; ++kt){
      v8bf a = AFRAG(kt);
      #pragma unroll
      for (int ct = 0; ct < 4; ++ct){
        v8bf b = *(const v8bf*)(lW + (((kt - 8)*8 + w)*4 + ct)*512 + lane*8);
        mfma_v(acc[ct], a, b);
      }
    }
    // MFMA->VALU hazard guard (asm MFMAs opaque to hazard recognizer)
    asm volatile("s_nop 7\n\ts_nop 7\n\ts_nop 7"
      : "+v"(acc[0]), "+v"(acc[1]), "+v"(acc[2]), "+v"(acc[3]));

    // elementwise: lane owns unit (s*128+unit), rows 4q+j
    #pragma unroll
    for (int j = 0; j < 4; ++j){
      float xi = acc[0][j], xf = acc[1][j], xg = acc[2][j], xo = acc[3][j];
      float cv = sigm(xf)*creg[j] + sigm(xi)*tanh_f(xg);
      float hv = sigm(xo)*tanh_f(cv);
      creg[j] = cv;
      int row = 4*q + j;
      u16 hb = f2bf(hv);
      *(u16*)(Anxt + row*AROWB + s*256 + unit*2) = hb;       // own A half
      if (n0 + row < NSEQ)                                    // publish = writeout
        hbuf[((size_t)(n0 + row)*TT + t)*HH + s*128 + unit] = hb;
    }
    // stage y[t+1]
    if (t + 1 < TT)
      *(unsigned*)(Anxt + srow*AROWB + 512 + schunk*4) = yv;

    __syncthreads();   // drains all waves' stores (vmcnt(0) before s_barrier)

    if (tid == 0){
      __builtin_amdgcn_fence(__ATOMIC_RELEASE, "agent");
      __hip_atomic_store(myflag, t + 1, __ATOMIC_RELAXED, __HIP_MEMORY_SCOPE_AGENT);
    }
    if (t + 1 < TT){
      while (__hip_atomic_load(otflag, __ATOMIC_RELAXED, __HIP_MEMORY_SCOPE_AGENT) < t + 1)
        __builtin_amdgcn_s_sleep(1);
      __builtin_amdgcn_fence(__ATOMIC_ACQUIRE, "agent");
      // stage partner half into Anxt
      uint2 hv = {0u, 0u};
      if (n0 + srow < NSEQ)
        hv = *(const uint2*)(hbuf + ((size_t)(n0 + srow)*TT + t)*HH + (s^1)*128 + schunk*4);
      *(uint2*)(Anxt + srow*AROWB + (s^1)*256 + schunk*8) = hv;
    }
    __syncthreads();
  }
}

// ---- out = h @ W_lin^T + b_lin, written as (B,OUT,F,T)
__global__ __launch_bounds__(256) void k_outproj(const u16* __restrict__ hbuf,
      const u16* __restrict__ wlin, const float* __restrict__ blin,
      float* __restrict__ out){
  extern __shared__ char smem[];
  u16* sA = (u16*)smem;                 // [128][264] rows = t
  u16* sB = (u16*)(smem + 128*264*2);   // [64][264]  rows = o
  const int n = blockIdx.x, th = blockIdx.y, t0 = th*128;
  const int b = n / 257, f = n % 257;
  const int tid = threadIdx.x, lane = tid & 63, wv = tid >> 6;

  for (int i = tid; i < 128*32; i += 256){
    int r = i >> 5, part = i & 31;
    *(uint4*)(sA + r*264 + part*8) =
        *(const uint4*)(hbuf + ((size_t)n*TT + t0 + r)*HH + part*8);
  }
  for (int i = tid; i < (64*264)/2; i += 256)
    ((unsigned*)sB)[i] = ((const unsigned*)wlin)[i];
  __syncthreads();

  f32x4 acc[2][4];
  #pragma unroll
  for (int m = 0; m < 2; ++m)
    #pragma unroll
    for (int nt = 0; nt < 4; ++nt){
      float bv = blin[nt*16 + (lane & 15)];
      acc[m][nt] = (f32x4){bv, bv, bv, bv};
    }
  const int khi = (lane >> 4) * 8;
  #pragma unroll
  for (int kt = 0; kt < 8; ++kt){
    v8bf av[2];
    #pragma unroll
    for (int m = 0; m < 2; ++m){
      int mt = wv*2 + m;
      av[m] = *(const v8bf*)(sA + (mt*16 + (lane & 15))*264 + kt*32 + khi);
    }
    #pragma unroll
    for (int nt = 0; nt < 4; ++nt){
      v8bf bv = *(const v8bf*)(sB + (nt*16 + (lane & 15))*264 + kt*32 + khi);
      #pragma unroll
      for (int m = 0; m < 2; ++m)
        acc[m][nt] = __builtin_amdgcn_mfma_f32_16x16x32_bf16(av[m], bv, acc[m][nt], 0, 0, 0);
    }
  }
  #pragma unroll
  for (int m = 0; m < 2; ++m){
    int mt = wv*2 + m;
    #pragma unroll
    for (int nt = 0; nt < 4; ++nt){
      int o = nt*16 + (lane & 15);
      int tb = t0 + mt*16 + 4*(lane >> 4);
      *(f32x4*)(out + (((size_t)b*64 + o)*257 + f)*TT + tb) = acc[m][nt];
    }
  }
}

extern "C" void kernel_launch(void* const* d_in, const int* in_sizes, int n_in,
                              void* d_out, int out_size, void* d_ws, size_t ws_size,
                              hipStream_t stream) {
  const float* x   = (const float*)d_in[0];
  const float* Wih = (const float*)d_in[1];
  const float* Whh = (const float*)d_in[2];
  const float* bih = (const float*)d_in[3];
  const float* bhh = (const float*)d_in[4];
  const float* Wl  = (const float*)d_in[5];
  const float* bl  = (const float*)d_in[6];
  float* out = (float*)d_out;

  char* p = (char*)d_ws;
  u16*   wpack = (u16*)p;   p += 655360;                 // 2 sides x 10 half-slabs
  float* bias  = (float*)p; p += 4096;
  u16*   wlin  = (u16*)p;   p += 33792;
  int*   flg   = (int*)p;   p += 65*2*32*4;              // 16640 -> pad
  p += 128;
  u16*   ybuf  = (u16*)p;   p += (size_t)NSEQ*TT*CC*2;   // 33.7 MB
  u16*   hbuf  = (u16*)p;                                // 134.7 MB

  hipFuncSetAttribute((const void*)k_lstm,    hipFuncAttributeMaxDynamicSharedMemorySize, LSTM_LDS);
  hipFuncSetAttribute((const void*)k_outproj, hipFuncAttributeMaxDynamicSharedMemorySize, OUTP_LDS);

  hipMemsetAsync(flg, 0, 65*2*32*4, stream);
  k_pack_w <<<1280, 256, 0, stream>>>(Whh, Wih, wpack);
  k_bias   <<<4,    256, 0, stream>>>(bih, bhh, bias);
  k_wlin   <<<66,   256, 0, stream>>>(Wl, wlin);
  k_ytrans <<<1028, 256, 0, stream>>>(x, ybuf);
  k_lstm   <<<144, 512, LSTM_LDS, stream>>>(wpack, bias, ybuf, hbuf, flg);
  k_outproj<<<dim3(1028, 2), 256, OUTP_LDS, stream>>>(hbuf, wlin, bl, out);
}

// Round 5
// 2957.569 us; speedup vs baseline: 1.0016x; 1.0016x over previous
//
#include <hip/hip_runtime.h>

#define NSEQ 1028
#define TT   256
#define CC   64
#define HH   256
#define AROWB 656                              // bytes per A row: 320*2 + 16 (stride ≡16 mod 128 → conflict-free b128)
#define HSLAB 16384                            // elems per (side,kt) half-slab: 8w*4ct*512
#define LSTM_LDS (2*16*AROWB + 2*2*HSLAB)      // 20992 + 65536 = 86528
#define OUTP_LDS (128*264*2 + 64*264*2)        // 101376

typedef unsigned short u16;
typedef float  f32x4 __attribute__((ext_vector_type(4)));
typedef __bf16 v8bf  __attribute__((ext_vector_type(8)));

__device__ __forceinline__ u16 f2bf(float f){
  unsigned u = __builtin_bit_cast(unsigned, f);
  u += 0x7FFFu + ((u >> 16) & 1u);
  return (u16)(u >> 16);
}
__device__ __forceinline__ float sigm(float x){
  float t = __builtin_amdgcn_exp2f(-1.4426950408889634f * x);
  return __builtin_amdgcn_rcpf(1.0f + t);
}
__device__ __forceinline__ float tanh_f(float x){
  float a = __builtin_fabsf(x);
  float t = __builtin_amdgcn_exp2f(-2.885390081777927f * a);
  float r = (1.0f - t) * __builtin_amdgcn_rcpf(1.0f + t);
  return __builtin_copysignf(r, x);
}
// MFMA with B pinned in AGPR (forces weight residency in accumulator file)
__device__ __forceinline__ void mfma_a(f32x4& d, v8bf a, v8bf b){
  asm("v_mfma_f32_16x16x32_bf16 %0, %1, %2, %0" : "+v"(d) : "v"(a), "a"(b));
}
__device__ __forceinline__ void mfma_v(f32x4& d, v8bf a, v8bf b){
  asm("v_mfma_f32_16x16x32_bf16 %0, %1, %2, %0" : "+v"(d) : "v"(a), "v"(b));
}

// ---- pack W into gate-split per-(side,kt,wave,ct) MFMA B-frags, bf16
// block-col c = ct*128 + w*16 + l15 -> global W row = ct*256 + s*128 + w*16 + l15
__global__ void k_pack_w(const float* __restrict__ Whh, const float* __restrict__ Wih,
                         u16* __restrict__ wpack){
  int idx = blockIdx.x*256 + threadIdx.x;
  if (idx >= 2*10*HSLAB) return;                // 327680
  int j    = idx & 7;
  int lane = (idx >> 3) & 63;
  int ct   = (idx >> 9) & 3;
  int w    = (idx >> 11) & 7;
  int rem  = idx >> 14;
  int kt   = rem % 10, s = rem / 10;
  int row  = ct*256 + s*128 + w*16 + (lane & 15);
  int k    = kt*32 + (lane >> 4)*8 + j;
  float v  = (k < 256) ? Whh[row*256 + k] : Wih[row*64 + (k - 256)];
  wpack[idx] = f2bf(v);
}

__global__ void k_bias(const float* __restrict__ bi, const float* __restrict__ bh,
                       float* __restrict__ bias){
  int i = blockIdx.x*256 + threadIdx.x;
  if (i < 1024) bias[i] = bi[i] + bh[i];
}

__global__ void k_wlin(const float* __restrict__ Wl, u16* __restrict__ wlin){
  int i = blockIdx.x*256 + threadIdx.x;
  if (i >= 64*264) return;
  int col = i / 264, k = i % 264;
  wlin[i] = (k < 256) ? f2bf(Wl[col*256 + k]) : (u16)0;
}

// ---- x(B,C,F,T) -> y(n,t,c) bf16, n = b*257+f
__global__ void k_ytrans(const float* __restrict__ x, u16* __restrict__ ybuf){
  __shared__ u16 tile[64][257];
  int n = blockIdx.x, b = n / 257, f = n % 257, tid = threadIdx.x;
  for (int i = tid; i < 64*256; i += 256){
    int c = i >> 8, t = i & 255;
    tile[c][t] = f2bf(x[((size_t)(b*64 + c)*257 + f)*256 + t]);
  }
  __syncthreads();
  for (int i = tid; i < 256*64; i += 256){
    int t = i >> 6, c = i & 63;
    ybuf[((size_t)n*256 + t)*64 + c] = tile[c][t];
  }
}

// ---- persistent gate-split LSTM: pair p = blocks {bx, bx+8}, side s = unit half
// Weights fully resident: kt0..7 AGPR (128/wave), kt8,9 (x-part) in LDS. No streaming.
// Per-step h-half exchange through hbuf (t-indexed, no reuse) + monotonic flags.
__global__ __launch_bounds__(512, 2) void k_lstm(const u16* __restrict__ wpack,
      const float* __restrict__ bias, const u16* __restrict__ ybuf,
      u16* __restrict__ hbuf, int* __restrict__ flg){
  const int bx = blockIdx.x;
  const int s = (bx >> 3) & 1;
  const int p = (bx & 7) + 8*(bx >> 4);
  if (p >= 65) return;                          // 130 active of 144
  extern __shared__ char smem[];
  char* lA = smem;                              // [2][16 rows][AROWB]
  u16*  lW = (u16*)(smem + 2*16*AROWB);         // kt8,9 half-slabs
  const int tid = threadIdx.x, lane = tid & 63, w = tid >> 6;
  const int n0 = p * 16;
  const int l15 = lane & 15, q = lane >> 4;
  const int srow = tid >> 5, schunk = tid & 31; // staging roles: 16 rows x 32 chunks
  const int unit = w*16 + l15;                  // local unit within half

  const u16* wbase = wpack + (size_t)s * (10*HSLAB);

  // AGPR-resident W (kt0..7): 128 AGPR/wave, pinned by "a"-constrained MFMA uses
  v8bf wreg[8][4];
  #pragma unroll
  for (int kt = 0; kt < 8; ++kt)
    #pragma unroll
    for (int ct = 0; ct < 4; ++ct)
      wreg[kt][ct] = *(const v8bf*)(wbase + ((kt*8 + w)*4 + ct)*512 + lane*8);

  { // LDS-resident W (kt8,9)
    const uint4* src = (const uint4*)(wbase + 8*HSLAB);
    uint4* dst = (uint4*)lW;
    for (int i = tid; i < (2*HSLAB)/8; i += 512) dst[i] = src[i];
  }
  float biasr[4];
  #pragma unroll
  for (int ct = 0; ct < 4; ++ct) biasr[ct] = bias[ct*256 + s*128 + unit];

  { // zero both A buffers (h(-1)=0)
    unsigned* z = (unsigned*)lA;
    for (int i = tid; i < (2*16*AROWB)/4; i += 512) z[i] = 0;
  }
  __syncthreads();
  { // stage y[t=0] into buf0
    unsigned v = 0;
    if (n0 + srow < NSEQ)
      v = *(const unsigned*)(ybuf + ((size_t)(n0 + srow)*TT + 0)*64 + schunk*2);
    *(unsigned*)(lA + srow*AROWB + 512 + schunk*4) = v;
  }
  f32x4 creg = (f32x4){0.f, 0.f, 0.f, 0.f};
  __syncthreads();

  int* myflag = flg + (p*2 + s)*32;
  int* otflag = flg + (p*2 + (s^1))*32;

  for (int t = 0; t < TT; ++t){
    char* Acur = lA + (t & 1)*16*AROWB;
    char* Anxt = lA + ((t + 1) & 1)*16*AROWB;

    // y prefetch for t+1
    unsigned yv = 0;
    if (t + 1 < TT && n0 + srow < NSEQ)
      yv = *(const unsigned*)(ybuf + ((size_t)(n0 + srow)*TT + (t + 1))*64 + schunk*2);

    f32x4 acc[4];
    #pragma unroll
    for (int ct = 0; ct < 4; ++ct)
      acc[ct] = (f32x4){biasr[ct], biasr[ct], biasr[ct], biasr[ct]};
    asm volatile("s_nop 1"
      : "+v"(acc[0]), "+v"(acc[1]), "+v"(acc[2]), "+v"(acc[3]));

    #define AFRAG(kt) (*(const v8bf*)(Acur + l15*AROWB + (kt)*64 + q*16))

    #pragma unroll
    for (int kt = 0; kt < 8; ++kt){
      v8bf a = AFRAG(kt);
      #pragma unroll
      for (int ct = 0; ct < 4; ++ct) mfma_a(acc[ct], a, wreg[kt][ct]);
    }
    #pragma unroll
    for (int kt = 8; kt < 10; ++kt){
      v8bf a = AFRAG(kt);
      #pragma unroll
      for (int ct = 0; ct < 4; ++ct){
        v8bf b = *(const v8bf*)(lW + (((kt - 8)*8 + w)*4 + ct)*512 + lane*8);
        mfma_v(acc[ct], a, b);
      }
    }
    // MFMA->VALU hazard guard (asm MFMAs opaque to hazard recognizer)
    asm volatile("s_nop 7\n\ts_nop 7\n\ts_nop 7"
      : "+v"(acc[0]), "+v"(acc[1]), "+v"(acc[2]), "+v"(acc[3]));

    // elementwise: lane owns unit (s*128+unit), rows 4q+j
    #pragma unroll
    for (int j = 0; j < 4; ++j){
      float xi = acc[0][j], xf = acc[1][j], xg = acc[2][j], xo = acc[3][j];
      float cv = sigm(xf)*creg[j] + sigm(xi)*tanh_f(xg);
      float hv = sigm(xo)*tanh_f(cv);
      creg[j] = cv;
      int row = 4*q + j;
      u16 hb = f2bf(hv);
      *(u16*)(Anxt + row*AROWB + s*256 + unit*2) = hb;       // own A half
      if (n0 + row < NSEQ)                                    // publish = writeout
        hbuf[((size_t)(n0 + row)*TT + t)*HH + s*128 + unit] = hb;
    }
    // stage y[t+1]
    if (t + 1 < TT)
      *(unsigned*)(Anxt + srow*AROWB + 512 + schunk*4) = yv;

    __syncthreads();   // drains all waves' stores (vmcnt(0) before s_barrier)

    if (tid == 0){
      __builtin_amdgcn_fence(__ATOMIC_RELEASE, "agent");
      __hip_atomic_store(myflag, t + 1, __ATOMIC_RELAXED, __HIP_MEMORY_SCOPE_AGENT);
    }
    if (t + 1 < TT){
      while (__hip_atomic_load(otflag, __ATOMIC_RELAXED, __HIP_MEMORY_SCOPE_AGENT) < t + 1)
        __builtin_amdgcn_s_sleep(1);
      __builtin_amdgcn_fence(__ATOMIC_ACQUIRE, "agent");
      // stage partner half into Anxt
      uint2 hv = {0u, 0u};
      if (n0 + srow < NSEQ)
        hv = *(const uint2*)(hbuf + ((size_t)(n0 + srow)*TT + t)*HH + (s^1)*128 + schunk*4);
      *(uint2*)(Anxt + srow*AROWB + (s^1)*256 + schunk*8) = hv;
    }
    __syncthreads();
  }
}

// ---- out = h @ W_lin^T + b_lin, written as (B,OUT,F,T)
__global__ __launch_bounds__(256) void k_outproj(const u16* __restrict__ hbuf,
      const u16* __restrict__ wlin, const float* __restrict__ blin,
      float* __restrict__ out){
  extern __shared__ char smem[];
  u16* sA = (u16*)smem;                 // [128][264] rows = t
  u16* sB = (u16*)(smem + 128*264*2);   // [64][264]  rows = o
  const int n = blockIdx.x, th = blockIdx.y, t0 = th*128;
  const int b = n / 257, f = n % 257;
  const int tid = threadIdx.x, lane = tid & 63, wv = tid >> 6;

  for (int i = tid; i < 128*32; i += 256){
    int r = i >> 5, part = i & 31;
    *(uint4*)(sA + r*264 + part*8) =
        *(const uint4*)(hbuf + ((size_t)n*TT + t0 + r)*HH + part*8);
  }
  for (int i = tid; i < (64*264)/2; i += 256)
    ((unsigned*)sB)[i] = ((const unsigned*)wlin)[i];
  __syncthreads();

  f32x4 acc[2][4];
  #pragma unroll
  for (int m = 0; m < 2; ++m)
    #pragma unroll
    for (int nt = 0; nt < 4; ++nt){
      float bv = blin[nt*16 + (lane & 15)];
      acc[m][nt] = (f32x4){bv, bv, bv, bv};
    }
  const int khi = (lane >> 4) * 8;
  #pragma unroll
  for (int kt = 0; kt < 8; ++kt){
    v8bf av[2];
    #pragma unroll
    for (int m = 0; m < 2; ++m){
      int mt = wv*2 + m;
      av[m] = *(const v8bf*)(sA + (mt*16 + (lane & 15))*264 + kt*32 + khi);
    }
    #pragma unroll
    for (int nt = 0; nt < 4; ++nt){
      v8bf bv = *(const v8bf*)(sB + (nt*16 + (lane & 15))*264 + kt*32 + khi);
      #pragma unroll
      for (int m = 0; m < 2; ++m)
        acc[m][nt] = __builtin_amdgcn_mfma_f32_16x16x32_bf16(av[m], bv, acc[m][nt], 0, 0, 0);
    }
  }
  #pragma unroll
  for (int m = 0; m < 2; ++m){
    int mt = wv*2 + m;
    #pragma unroll
    for (int nt = 0; nt < 4; ++nt){
      int o = nt*16 + (lane & 15);
      int tb = t0 + mt*16 + 4*(lane >> 4);
      *(f32x4*)(out + (((size_t)b*64 + o)*257 + f)*TT + tb) = acc[m][nt];
    }
  }
}

extern "C" void kernel_launch(void* const* d_in, const int* in_sizes, int n_in,
                              void* d_out, int out_size, void* d_ws, size_t ws_size,
                              hipStream_t stream) {
  const float* x   = (const float*)d_in[0];
  const float* Wih = (const float*)d_in[1];
  const float* Whh = (const float*)d_in[2];
  const float* bih = (const float*)d_in[3];
  const float* bhh = (const float*)d_in[4];
  const float* Wl  = (const float*)d_in[5];
  const float* bl  = (const float*)d_in[6];
  float* out = (float*)d_out;

  char* p = (char*)d_ws;
  u16*   wpack = (u16*)p;   p += 655360;                 // 2 sides x 10 half-slabs
  float* bias  = (float*)p; p += 4096;
  u16*   wlin  = (u16*)p;   p += 33792;
  int*   flg   = (int*)p;   p += 65*2*32*4;              // 16640 -> pad
  p += 128;
  u16*   ybuf  = (u16*)p;   p += (size_t)NSEQ*TT*CC*2;   // 33.7 MB
  u16*   hbuf  = (u16*)p;                                // 134.7 MB

  hipFuncSetAttribute((const void*)k_lstm,    hipFuncAttributeMaxDynamicSharedMemorySize, LSTM_LDS);
  hipFuncSetAttribute((const void*)k_outproj, hipFuncAttributeMaxDynamicSharedMemorySize, OUTP_LDS);

  hipMemsetAsync(flg, 0, 65*2*32*4, stream);
  k_pack_w <<<1280, 256, 0, stream>>>(Whh, Wih, wpack);
  k_bias   <<<4,    256, 0, stream>>>(bih, bhh, bias);
  k_wlin   <<<66,   256, 0, stream>>>(Wl, wlin);
  k_ytrans <<<1028, 256, 0, stream>>>(x, ybuf);
  k_lstm   <<<144, 512, LSTM_LDS, stream>>>(wpack, bias, ybuf, hbuf, flg);
  k_outproj<<<dim3(1028, 2), 256, OUTP_LDS, stream>>>(hbuf, wlin, bl, out);
}

// Round 6
// 1594.573 us; speedup vs baseline: 1.8577x; 1.8548x over previous
//
#include <hip/hip_runtime.h>

#define NSEQ 1028
#define TT   256
#define CC   64
#define HH   256
#define NKT  10               // k-tiles of 32 (8 for W_hh, 2 for W_ih)
#define AROWB 656             // bytes per A row: 320*2 + 16 pad (16 mod 128 -> conflict-free b128)
#define SLABE 32768           // elems per kt slab: 8 waves * 8 ct * 512
#define LSTM_LDS (2*16*AROWB + 2*SLABE*2)   // 20992 + 131072 = 152064
#define OUTP_LDS (128*264*2 + 64*264*2)     // 101376

typedef unsigned short u16;
typedef float  f32x4 __attribute__((ext_vector_type(4)));
typedef __bf16 v8bf  __attribute__((ext_vector_type(8)));

__device__ __forceinline__ u16 f2bf(float f){
  unsigned u = __builtin_bit_cast(unsigned, f);
  u += 0x7FFFu + ((u >> 16) & 1u);
  return (u16)(u >> 16);
}
__device__ __forceinline__ float sigm(float x){
  float t = __builtin_amdgcn_exp2f(-1.4426950408889634f * x);
  return __builtin_amdgcn_rcpf(1.0f + t);
}
__device__ __forceinline__ float tanh_f(float x){
  float a = __builtin_fabsf(x);
  float t = __builtin_amdgcn_exp2f(-2.885390081777927f * a);
  float r = (1.0f - t) * __builtin_amdgcn_rcpf(1.0f + t);
  return __builtin_copysignf(r, x);
}
// MFMA with B pinned in AGPR (weight residency in accumulator file)
__device__ __forceinline__ void mfma_a(f32x4& d, v8bf a, v8bf b){
  asm("v_mfma_f32_16x16x32_bf16 %0, %1, %2, %0" : "+v"(d) : "v"(a), "a"(b));
}
// MFMA with B in arch VGPR (LDS-sourced / streamed tiles)
__device__ __forceinline__ void mfma_v(f32x4& d, v8bf a, v8bf b){
  asm("v_mfma_f32_16x16x32_bf16 %0, %1, %2, %0" : "+v"(d) : "v"(a), "v"(b));
}

// ---- pack W = [W_hh | W_ih] into per-(kt,wave,ct) MFMA B-frags, bf16
__global__ void k_pack_w(const float* __restrict__ Whh, const float* __restrict__ Wih,
                         u16* __restrict__ wpack){
  int idx = blockIdx.x*256 + threadIdx.x;
  if (idx >= NKT*SLABE) return;                 // 327680
  int j    = idx & 7;
  int lane = (idx >> 3) & 63;
  int ct   = (idx >> 9) & 7;
  int w    = (idx >> 12) & 7;
  int kt   = idx >> 15;
  int col  = (ct >> 1)*256 + w*32 + (ct & 1)*16 + (lane & 15);
  int k    = kt*32 + (lane >> 4)*8 + j;
  float v  = (k < 256) ? Whh[col*256 + k] : Wih[col*64 + (k - 256)];
  wpack[idx] = f2bf(v);
}

__global__ void k_bias(const float* __restrict__ bi, const float* __restrict__ bh,
                       float* __restrict__ bias){
  int i = blockIdx.x*256 + threadIdx.x;
  if (i < 1024) bias[i] = bi[i] + bh[i];
}

__global__ void k_wlin(const float* __restrict__ Wl, u16* __restrict__ wlin){
  int i = blockIdx.x*256 + threadIdx.x;
  if (i >= 64*264) return;
  int col = i / 264, k = i % 264;
  wlin[i] = (k < 256) ? f2bf(Wl[col*256 + k]) : (u16)0;
}

// ---- x(B,C,F,T) -> y(n,t,c) bf16, n = b*257+f
__global__ void k_ytrans(const float* __restrict__ x, u16* __restrict__ ybuf){
  __shared__ u16 tile[64][257];
  int n = blockIdx.x, b = n / 257, f = n % 257, tid = threadIdx.x;
  for (int i = tid; i < 64*256; i += 256){
    int c = i >> 8, t = i & 255;
    tile[c][t] = f2bf(x[((size_t)(b*64 + c)*257 + f)*256 + t]);
  }
  __syncthreads();
  for (int i = tid; i < 256*64; i += 256){
    int t = i >> 6, c = i & 63;
    ybuf[((size_t)n*256 + t)*64 + c] = tile[c][t];
  }
}

// ---- persistent LSTM: 65 blocks x 512 thr (8 waves), 16 seqs/block, no inter-block sync.
// Residency budget (256 regs/wave at 2 waves/SIMD): 128 AGPR (kt0..3) + ~110 arch.
// kt4,5 in LDS (128 KB). kt6..9 streamed from L2 via one rolling 32-reg buffer.
__global__ __launch_bounds__(512, 2) void k_lstm(const u16* __restrict__ wpack,
      const float* __restrict__ bias, const u16* __restrict__ ybuf,
      u16* __restrict__ hbuf){
  extern __shared__ char smem[];
  char* lA = smem;                              // [2][16 rows][AROWB]
  u16*  lW = (u16*)(smem + 2*16*AROWB);         // kt4,5 slabs
  const int tid = threadIdx.x, lane = tid & 63, w = tid >> 6;   // w 0..7
  const int n0 = blockIdx.x * 16;
  const int l15 = lane & 15, q = lane >> 4;
  const int srow = tid >> 5, schunk = tid & 31; // staging roles: 16 rows x 32 chunks

  // AGPR-resident W (kt0..3): exactly 128 AGPR/wave, pinned by "a"-constrained uses
  v8bf wreg[4][8];
  #pragma unroll
  for (int kt = 0; kt < 4; ++kt)
    #pragma unroll
    for (int ct = 0; ct < 8; ++ct)
      wreg[kt][ct] = *(const v8bf*)(wpack + ((kt*8 + w)*8 + ct)*512 + lane*8);

  { // LDS-resident W (kt4,5)
    const uint4* src = (const uint4*)(wpack + 4*SLABE);
    uint4* dst = (uint4*)lW;
    for (int i = tid; i < (2*SLABE)/8; i += 512) dst[i] = src[i];
  }
  float biasr[8];
  #pragma unroll
  for (int ct = 0; ct < 8; ++ct)
    biasr[ct] = bias[(ct >> 1)*256 + w*32 + (ct & 1)*16 + l15];

  { // zero both A buffers (h(-1)=0)
    unsigned* z = (unsigned*)lA;
    for (int i = tid; i < (2*16*AROWB)/4; i += 512) z[i] = 0;
  }
  __syncthreads();
  { // stage y[t=0] into buf0
    unsigned v = 0;
    if (n0 + srow < NSEQ)
      v = *(const unsigned*)(ybuf + ((size_t)(n0 + srow)*TT + 0)*64 + schunk*2);
    *(unsigned*)(lA + srow*AROWB + 512 + schunk*4) = v;
  }
  f32x4 creg[2];
  creg[0] = (f32x4){0.f,0.f,0.f,0.f};
  creg[1] = (f32x4){0.f,0.f,0.f,0.f};
  __syncthreads();

  const u16* wp = wpack;           // opaque-refreshed each step (defeats LICM)

  for (int t = 0; t < TT; ++t){
    char* Acur = lA + (t & 1)*16*AROWB;
    char* Anxt = lA + ((t + 1) & 1)*16*AROWB;

    asm("" : "+s"(wp));            // loads below may not be hoisted out of the loop
    const u16* wpw = wp + w*4096 + lane*8;

    // issue stream kt6 (single rolling buffer; used after kt0,kt1)
    v8bf sbuf[8];
    #pragma unroll
    for (int ct = 0; ct < 8; ++ct) sbuf[ct] = *(const v8bf*)(wpw + 6*SLABE + ct*512);

    // y prefetch for t+1
    unsigned yv = 0;
    if (t + 1 < TT && n0 + srow < NSEQ)
      yv = *(const unsigned*)(ybuf + ((size_t)(n0 + srow)*TT + (t + 1))*64 + schunk*2);

    // h(t-1) writeout (overlaps MFMA)
    if (t >= 1 && n0 + srow < NSEQ){
      uint4 hv = *(const uint4*)(Acur + srow*AROWB + schunk*16);
      *(uint4*)(hbuf + ((size_t)(n0 + srow)*TT + (t - 1))*HH + schunk*8) = hv;
    }

    f32x4 acc[8];
    #pragma unroll
    for (int ct = 0; ct < 8; ++ct)
      acc[ct] = (f32x4){biasr[ct], biasr[ct], biasr[ct], biasr[ct]};
    asm volatile("s_nop 1"
      : "+v"(acc[0]), "+v"(acc[1]), "+v"(acc[2]), "+v"(acc[3]),
        "+v"(acc[4]), "+v"(acc[5]), "+v"(acc[6]), "+v"(acc[7]));

    #define AFRAG(kt) (*(const v8bf*)(Acur + l15*AROWB + (kt)*64 + q*16))
    #define LFRAG(kt,ct) (*(const v8bf*)(lW + (((kt)-4)*8 + w)*4096 + (ct)*512 + lane*8))

    { v8bf a = AFRAG(0);                         // kt0 (AGPR)
      #pragma unroll
      for (int ct = 0; ct < 8; ++ct) mfma_a(acc[ct], a, wreg[0][ct]); }
    { v8bf a = AFRAG(1);                         // kt1 (AGPR)
      #pragma unroll
      for (int ct = 0; ct < 8; ++ct) mfma_a(acc[ct], a, wreg[1][ct]); }
    { v8bf a = AFRAG(6);                         // kt6 (stream), refill <- kt7
      #pragma unroll
      for (int ct = 0; ct < 8; ++ct) mfma_v(acc[ct], a, sbuf[ct]);
      #pragma unroll
      for (int ct = 0; ct < 8; ++ct) sbuf[ct] = *(const v8bf*)(wpw + 7*SLABE + ct*512); }
    { v8bf a = AFRAG(2);                         // kt2 (AGPR)
      #pragma unroll
      for (int ct = 0; ct < 8; ++ct) mfma_a(acc[ct], a, wreg[2][ct]); }
    { v8bf a = AFRAG(3);                         // kt3 (AGPR)
      #pragma unroll
      for (int ct = 0; ct < 8; ++ct) mfma_a(acc[ct], a, wreg[3][ct]); }
    { v8bf a = AFRAG(7);                         // kt7 (stream), refill <- kt8
      #pragma unroll
      for (int ct = 0; ct < 8; ++ct) mfma_v(acc[ct], a, sbuf[ct]);
      #pragma unroll
      for (int ct = 0; ct < 8; ++ct) sbuf[ct] = *(const v8bf*)(wpw + 8*SLABE + ct*512); }
    { v8bf a = AFRAG(4);                         // kt4 (LDS)
      #pragma unroll
      for (int ct = 0; ct < 8; ++ct) mfma_v(acc[ct], a, LFRAG(4,ct)); }
    { v8bf a = AFRAG(8);                         // kt8 (stream), refill <- kt9
      #pragma unroll
      for (int ct = 0; ct < 8; ++ct) mfma_v(acc[ct], a, sbuf[ct]);
      #pragma unroll
      for (int ct = 0; ct < 8; ++ct) sbuf[ct] = *(const v8bf*)(wpw + 9*SLABE + ct*512); }
    { v8bf a = AFRAG(5);                         // kt5 (LDS)
      #pragma unroll
      for (int ct = 0; ct < 8; ++ct) mfma_v(acc[ct], a, LFRAG(5,ct)); }
    { v8bf a = AFRAG(9);                         // kt9 (stream)
      #pragma unroll
      for (int ct = 0; ct < 8; ++ct) mfma_v(acc[ct], a, sbuf[ct]); }

    // MFMA->VALU hazard guard (asm MFMAs opaque to hazard recognizer)
    asm volatile("s_nop 7\n\ts_nop 7\n\ts_nop 7"
      : "+v"(acc[0]), "+v"(acc[1]), "+v"(acc[2]), "+v"(acc[3]),
        "+v"(acc[4]), "+v"(acc[5]), "+v"(acc[6]), "+v"(acc[7]));

    // elementwise cell update: lane owns units w*32+u*16+l15, rows 4q+j
    #pragma unroll
    for (int u = 0; u < 2; ++u){
      #pragma unroll
      for (int j = 0; j < 4; ++j){
        float xi = acc[0 + u][j], xf = acc[2 + u][j], xg = acc[4 + u][j], xo = acc[6 + u][j];
        float cv = sigm(xf)*creg[u][j] + sigm(xi)*tanh_f(xg);
        float hv = sigm(xo)*tanh_f(cv);
        creg[u][j] = cv;
        int row = 4*q + j, unit = w*32 + u*16 + l15;
        *(u16*)(Anxt + row*AROWB + unit*2) = f2bf(hv);
      }
    }
    // stage y[t+1]
    if (t + 1 < TT)
      *(unsigned*)(Anxt + srow*AROWB + 512 + schunk*4) = yv;
    __syncthreads();
  }
  { // final h[255] sits in buf (TT&1)=0
    char* Afin = lA + (TT & 1)*16*AROWB;
    if (n0 + srow < NSEQ){
      uint4 hv = *(const uint4*)(Afin + srow*AROWB + schunk*16);
      *(uint4*)(hbuf + ((size_t)(n0 + srow)*TT + (TT - 1))*HH + schunk*8) = hv;
    }
  }
}

// ---- out = h @ W_lin^T + b_lin, written as (B,OUT,F,T)
__global__ __launch_bounds__(256) void k_outproj(const u16* __restrict__ hbuf,
      const u16* __restrict__ wlin, const float* __restrict__ blin,
      float* __restrict__ out){
  extern __shared__ char smem[];
  u16* sA = (u16*)smem;                 // [128][264] rows = t
  u16* sB = (u16*)(smem + 128*264*2);   // [64][264]  rows = o
  const int n = blockIdx.x, th = blockIdx.y, t0 = th*128;
  const int b = n / 257, f = n % 257;
  const int tid = threadIdx.x, lane = tid & 63, wv = tid >> 6;

  for (int i = tid; i < 128*32; i += 256){
    int r = i >> 5, part = i & 31;
    *(uint4*)(sA + r*264 + part*8) =
        *(const uint4*)(hbuf + ((size_t)n*TT + t0 + r)*HH + part*8);
  }
  for (int i = tid; i < (64*264)/2; i += 256)
    ((unsigned*)sB)[i] = ((const unsigned*)wlin)[i];
  __syncthreads();

  f32x4 acc[2][4];
  #pragma unroll
  for (int m = 0; m < 2; ++m)
    #pragma unroll
    for (int nt = 0; nt < 4; ++nt){
      float bv = blin[nt*16 + (lane & 15)];
      acc[m][nt] = (f32x4){bv, bv, bv, bv};
    }
  const int khi = (lane >> 4) * 8;
  #pragma unroll
  for (int kt = 0; kt < 8; ++kt){
    v8bf av[2];
    #pragma unroll
    for (int m = 0; m < 2; ++m){
      int mt = wv*2 + m;
      av[m] = *(const v8bf*)(sA + (mt*16 + (lane & 15))*264 + kt*32 + khi);
    }
    #pragma unroll
    for (int nt = 0; nt < 4; ++nt){
      v8bf bv = *(const v8bf*)(sB + (nt*16 + (lane & 15))*264 + kt*32 + khi);
      #pragma unroll
      for (int m = 0; m < 2; ++m)
        acc[m][nt] = __builtin_amdgcn_mfma_f32_16x16x32_bf16(av[m], bv, acc[m][nt], 0, 0, 0);
    }
  }
  #pragma unroll
  for (int m = 0; m < 2; ++m){
    int mt = wv*2 + m;
    #pragma unroll
    for (int nt = 0; nt < 4; ++nt){
      int o = nt*16 + (lane & 15);
      int tb = t0 + mt*16 + 4*(lane >> 4);
      *(f32x4*)(out + (((size_t)b*64 + o)*257 + f)*TT + tb) = acc[m][nt];
    }
  }
}

extern "C" void kernel_launch(void* const* d_in, const int* in_sizes, int n_in,
                              void* d_out, int out_size, void* d_ws, size_t ws_size,
                              hipStream_t stream) {
  const float* x   = (const float*)d_in[0];
  const float* Wih = (const float*)d_in[1];
  const float* Whh = (const float*)d_in[2];
  const float* bih = (const float*)d_in[3];
  const float* bhh = (const float*)d_in[4];
  const float* Wl  = (const float*)d_in[5];
  const float* bl  = (const float*)d_in[6];
  float* out = (float*)d_out;

  char* p = (char*)d_ws;
  u16*   wpack = (u16*)p;   p += 655360;                 // 10 slabs
  float* bias  = (float*)p; p += 4096;
  u16*   wlin  = (u16*)p;   p += 33792;
  u16*   ybuf  = (u16*)p;   p += (size_t)NSEQ*TT*CC*2;   // 33.7 MB
  u16*   hbuf  = (u16*)p;                                // 134.7 MB

  hipFuncSetAttribute((const void*)k_lstm,    hipFuncAttributeMaxDynamicSharedMemorySize, LSTM_LDS);
  hipFuncSetAttribute((const void*)k_outproj, hipFuncAttributeMaxDynamicSharedMemorySize, OUTP_LDS);

  k_pack_w <<<1280, 256, 0, stream>>>(Whh, Wih, wpack);
  k_bias   <<<4,    256, 0, stream>>>(bih, bhh, bias);
  k_wlin   <<<66,   256, 0, stream>>>(Wl, wlin);
  k_ytrans <<<1028, 256, 0, stream>>>(x, ybuf);
  k_lstm   <<<65, 512, LSTM_LDS, stream>>>(wpack, bias, ybuf, hbuf);
  k_outproj<<<dim3(1028, 2), 256, OUTP_LDS, stream>>>(hbuf, wlin, bl, out);
}

// Round 7
// 1201.452 us; speedup vs baseline: 2.4655x; 1.3272x over previous
//
#include <hip/hip_runtime.h>

#define NSEQ 1028
#define TT   256
#define CC   64
#define HH   256
#define NKT  10               // k-tiles of 32 (8 for W_hh, 2 for W_ih)
#define AROWB 656             // bytes per A row: 320*2 + 16 pad (16 mod 128 -> conflict-free b128)
#define SLABE 32768           // elems per kt slab: 8 waves * 8 ct * 512
#define LSTM_LDS (2*16*AROWB + 2*SLABE*2)   // 20992 + 131072 = 152064
#define OUTP_LDS (128*264*2 + 64*264*2)     // 101376

typedef unsigned short u16;
typedef float  f32x4 __attribute__((ext_vector_type(4)));
typedef __bf16 v8bf  __attribute__((ext_vector_type(8)));

__device__ __forceinline__ u16 f2bf(float f){
  unsigned u = __builtin_bit_cast(unsigned, f);
  u += 0x7FFFu + ((u >> 16) & 1u);
  return (u16)(u >> 16);
}
__device__ __forceinline__ float sigm(float x){
  float t = __builtin_amdgcn_exp2f(-1.4426950408889634f * x);
  return __builtin_amdgcn_rcpf(1.0f + t);
}
__device__ __forceinline__ float tanh_f(float x){
  float a = __builtin_fabsf(x);
  float t = __builtin_amdgcn_exp2f(-2.885390081777927f * a);
  float r = (1.0f - t) * __builtin_amdgcn_rcpf(1.0f + t);
  return __builtin_copysignf(r, x);
}
// MFMA with B pinned in AGPR (weight residency in accumulator file)
__device__ __forceinline__ void mfma_a(f32x4& d, v8bf a, v8bf b){
  asm("v_mfma_f32_16x16x32_bf16 %0, %1, %2, %0" : "+v"(d) : "v"(a), "a"(b));
}
// MFMA with B in arch VGPR (LDS-sourced / streamed tiles)
__device__ __forceinline__ void mfma_v(f32x4& d, v8bf a, v8bf b){
  asm("v_mfma_f32_16x16x32_bf16 %0, %1, %2, %0" : "+v"(d) : "v"(a), "v"(b));
}

// ---- pack W = [W_hh | W_ih] into per-(kt,wave,ct) MFMA B-frags, bf16
__global__ void k_pack_w(const float* __restrict__ Whh, const float* __restrict__ Wih,
                         u16* __restrict__ wpack){
  int idx = blockIdx.x*256 + threadIdx.x;
  if (idx >= NKT*SLABE) return;                 // 327680
  int j    = idx & 7;
  int lane = (idx >> 3) & 63;
  int ct   = (idx >> 9) & 7;
  int w    = (idx >> 12) & 7;
  int kt   = idx >> 15;
  int col  = (ct >> 1)*256 + w*32 + (ct & 1)*16 + (lane & 15);
  int k    = kt*32 + (lane >> 4)*8 + j;
  float v  = (k < 256) ? Whh[col*256 + k] : Wih[col*64 + (k - 256)];
  wpack[idx] = f2bf(v);
}

__global__ void k_bias(const float* __restrict__ bi, const float* __restrict__ bh,
                       float* __restrict__ bias){
  int i = blockIdx.x*256 + threadIdx.x;
  if (i < 1024) bias[i] = bi[i] + bh[i];
}

__global__ void k_wlin(const float* __restrict__ Wl, u16* __restrict__ wlin){
  int i = blockIdx.x*256 + threadIdx.x;
  if (i >= 64*264) return;
  int col = i / 264, k = i % 264;
  wlin[i] = (k < 256) ? f2bf(Wl[col*256 + k]) : (u16)0;
}

// ---- x(B,C,F,T) -> y(n,t,c) bf16, n = b*257+f
__global__ void k_ytrans(const float* __restrict__ x, u16* __restrict__ ybuf){
  __shared__ u16 tile[64][257];
  int n = blockIdx.x, b = n / 257, f = n % 257, tid = threadIdx.x;
  for (int i = tid; i < 64*256; i += 256){
    int c = i >> 8, t = i & 255;
    tile[c][t] = f2bf(x[((size_t)(b*64 + c)*257 + f)*256 + t]);
  }
  __syncthreads();
  for (int i = tid; i < 256*64; i += 256){
    int t = i >> 6, c = i & 63;
    ybuf[((size_t)n*256 + t)*64 + c] = tile[c][t];
  }
}

// ---- persistent LSTM: 65 blocks x 512 thr (8 waves), 16 seqs/block.
// Residency: kt0..3 AGPR (128/wave), kt4,5 LDS (128 KB), kt6..9 streamed.
// Stream rotation with cross-step prefetch: every load issued one slot before
// its consuming MFMA block; kt6's load spans the whole cell+barrier phase.
__global__ __launch_bounds__(512, 2) void k_lstm(const u16* __restrict__ wpack,
      const float* __restrict__ bias, const u16* __restrict__ ybuf,
      u16* __restrict__ hbuf){
  extern __shared__ char smem[];
  char* lA = smem;                              // [2][16 rows][AROWB]
  u16*  lW = (u16*)(smem + 2*16*AROWB);         // kt4,5 slabs
  const int tid = threadIdx.x, lane = tid & 63, w = tid >> 6;   // w 0..7
  const int n0 = blockIdx.x * 16;
  const int l15 = lane & 15, q = lane >> 4;
  const int srow = tid >> 5, schunk = tid & 31; // staging roles: 16 rows x 32 chunks

  // AGPR-resident W (kt0..3): exactly 128 AGPR/wave, pinned by "a"-constrained uses
  v8bf wreg[4][8];
  #pragma unroll
  for (int kt = 0; kt < 4; ++kt)
    #pragma unroll
    for (int ct = 0; ct < 8; ++ct)
      wreg[kt][ct] = *(const v8bf*)(wpack + ((kt*8 + w)*8 + ct)*512 + lane*8);

  { // LDS-resident W (kt4,5)
    const uint4* src = (const uint4*)(wpack + 4*SLABE);
    uint4* dst = (uint4*)lW;
    for (int i = tid; i < (2*SLABE)/8; i += 512) dst[i] = src[i];
  }
  float biasr[8];
  #pragma unroll
  for (int ct = 0; ct < 8; ++ct)
    biasr[ct] = bias[(ct >> 1)*256 + w*32 + (ct & 1)*16 + l15];

  { // zero both A buffers (h(-1)=0)
    unsigned* z = (unsigned*)lA;
    for (int i = tid; i < (2*16*AROWB)/4; i += 512) z[i] = 0;
  }
  __syncthreads();
  { // stage y[t=0] into buf0
    unsigned v = 0;
    if (n0 + srow < NSEQ)
      v = *(const unsigned*)(ybuf + ((size_t)(n0 + srow)*TT + 0)*64 + schunk*2);
    *(unsigned*)(lA + srow*AROWB + 512 + schunk*4) = v;
  }
  f32x4 creg[2];
  creg[0] = (f32x4){0.f,0.f,0.f,0.f};
  creg[1] = (f32x4){0.f,0.f,0.f,0.f};
  __syncthreads();

  const u16* wp = wpack;           // opaque-refreshed each step (defeats LICM/CSE)

  // prologue: issue kt6 for t=0 (consumed after kt0,kt1 next)
  v8bf sbuf[8];
  {
    const u16* wpw0 = wp + w*4096 + lane*8;
    #pragma unroll
    for (int ct = 0; ct < 8; ++ct) sbuf[ct] = *(const v8bf*)(wpw0 + 6*SLABE + ct*512);
  }

  for (int t = 0; t < TT; ++t){
    char* Acur = lA + (t & 1)*16*AROWB;
    char* Anxt = lA + ((t + 1) & 1)*16*AROWB;

    asm("" : "+s"(wp));            // fresh base each iteration
    const u16* wpw = wp + w*4096 + lane*8;

    // y prefetch for t+1 (consumed at staging, pre-barrier)
    unsigned yv = 0;
    if (t + 1 < TT && n0 + srow < NSEQ)
      yv = *(const unsigned*)(ybuf + ((size_t)(n0 + srow)*TT + (t + 1))*64 + schunk*2);

    // h(t-1) writeout (fire-and-forget, overlaps MFMA)
    if (t >= 1 && n0 + srow < NSEQ){
      uint4 hv = *(const uint4*)(Acur + srow*AROWB + schunk*16);
      *(uint4*)(hbuf + ((size_t)(n0 + srow)*TT + (t - 1))*HH + schunk*8) = hv;
    }

    f32x4 acc[8];
    #pragma unroll
    for (int ct = 0; ct < 8; ++ct)
      acc[ct] = (f32x4){biasr[ct], biasr[ct], biasr[ct], biasr[ct]};
    asm volatile("s_nop 1"
      : "+v"(acc[0]), "+v"(acc[1]), "+v"(acc[2]), "+v"(acc[3]),
        "+v"(acc[4]), "+v"(acc[5]), "+v"(acc[6]), "+v"(acc[7]));

    #define AFRAG(kt) (*(const v8bf*)(Acur + l15*AROWB + (kt)*64 + q*16))
    #define LFRAG(kt,ct) (*(const v8bf*)(lW + (((kt)-4)*8 + w)*4096 + (ct)*512 + lane*8))

    { v8bf a = AFRAG(0);                         // kt0 (AGPR)
      #pragma unroll
      for (int ct = 0; ct < 8; ++ct) mfma_a(acc[ct], a, wreg[0][ct]); }
    { v8bf a = AFRAG(1);                         // kt1 (AGPR)
      #pragma unroll
      for (int ct = 0; ct < 8; ++ct) mfma_a(acc[ct], a, wreg[1][ct]); }
    { v8bf a = AFRAG(6);                         // kt6 (loaded prev step) -> refill kt7
      #pragma unroll
      for (int ct = 0; ct < 8; ++ct) mfma_v(acc[ct], a, sbuf[ct]);
      #pragma unroll
      for (int ct = 0; ct < 8; ++ct) sbuf[ct] = *(const v8bf*)(wpw + 7*SLABE + ct*512);
      __builtin_amdgcn_sched_barrier(0); }
    { v8bf a = AFRAG(2);                         // kt2 (AGPR)
      #pragma unroll
      for (int ct = 0; ct < 8; ++ct) mfma_a(acc[ct], a, wreg[2][ct]); }
    { v8bf a = AFRAG(3);                         // kt3 (AGPR)
      #pragma unroll
      for (int ct = 0; ct < 8; ++ct) mfma_a(acc[ct], a, wreg[3][ct]); }
    { v8bf a = AFRAG(7);                         // kt7 -> refill kt8
      #pragma unroll
      for (int ct = 0; ct < 8; ++ct) mfma_v(acc[ct], a, sbuf[ct]);
      #pragma unroll
      for (int ct = 0; ct < 8; ++ct) sbuf[ct] = *(const v8bf*)(wpw + 8*SLABE + ct*512);
      __builtin_amdgcn_sched_barrier(0); }
    { v8bf a = AFRAG(4);                         // kt4 (LDS)
      #pragma unroll
      for (int ct = 0; ct < 8; ++ct) mfma_v(acc[ct], a, LFRAG(4,ct)); }
    { v8bf a = AFRAG(8);                         // kt8 -> refill kt9
      #pragma unroll
      for (int ct = 0; ct < 8; ++ct) mfma_v(acc[ct], a, sbuf[ct]);
      #pragma unroll
      for (int ct = 0; ct < 8; ++ct) sbuf[ct] = *(const v8bf*)(wpw + 9*SLABE + ct*512);
      __builtin_amdgcn_sched_barrier(0); }
    { v8bf a = AFRAG(5);                         // kt5 (LDS)
      #pragma unroll
      for (int ct = 0; ct < 8; ++ct) mfma_v(acc[ct], a, LFRAG(5,ct)); }
    { v8bf a = AFRAG(9);                         // kt9 -> refill kt6 for t+1
      #pragma unroll
      for (int ct = 0; ct < 8; ++ct) mfma_v(acc[ct], a, sbuf[ct]);
      #pragma unroll
      for (int ct = 0; ct < 8; ++ct) sbuf[ct] = *(const v8bf*)(wpw + 6*SLABE + ct*512);
      __builtin_amdgcn_sched_barrier(0); }

    // MFMA->VALU hazard guard (asm MFMAs opaque to hazard recognizer)
    asm volatile("s_nop 7\n\ts_nop 7\n\ts_nop 7"
      : "+v"(acc[0]), "+v"(acc[1]), "+v"(acc[2]), "+v"(acc[3]),
        "+v"(acc[4]), "+v"(acc[5]), "+v"(acc[6]), "+v"(acc[7]));

    // elementwise cell update: lane owns units w*32+u*16+l15, rows 4q+j
    // (kt6' loads for t+1 are in flight under this whole phase)
    #pragma unroll
    for (int u = 0; u < 2; ++u){
      #pragma unroll
      for (int j = 0; j < 4; ++j){
        float xi = acc[0 + u][j], xf = acc[2 + u][j], xg = acc[4 + u][j], xo = acc[6 + u][j];
        float cv = sigm(xf)*creg[u][j] + sigm(xi)*tanh_f(xg);
        float hv = sigm(xo)*tanh_f(cv);
        creg[u][j] = cv;
        int row = 4*q + j, unit = w*32 + u*16 + l15;
        *(u16*)(Anxt + row*AROWB + unit*2) = f2bf(hv);
      }
    }
    // stage y[t+1]
    if (t + 1 < TT)
      *(unsigned*)(Anxt + srow*AROWB + 512 + schunk*4) = yv;
    __syncthreads();
  }
  { // final h[255] sits in buf (TT&1)=0
    char* Afin = lA + (TT & 1)*16*AROWB;
    if (n0 + srow < NSEQ){
      uint4 hv = *(const uint4*)(Afin + srow*AROWB + schunk*16);
      *(uint4*)(hbuf + ((size_t)(n0 + srow)*TT + (TT - 1))*HH + schunk*8) = hv;
    }
  }
}

// ---- out = h @ W_lin^T + b_lin, written as (B,OUT,F,T)
__global__ __launch_bounds__(256) void k_outproj(const u16* __restrict__ hbuf,
      const u16* __restrict__ wlin, const float* __restrict__ blin,
      float* __restrict__ out){
  extern __shared__ char smem[];
  u16* sA = (u16*)smem;                 // [128][264] rows = t
  u16* sB = (u16*)(smem + 128*264*2);   // [64][264]  rows = o
  const int n = blockIdx.x, th = blockIdx.y, t0 = th*128;
  const int b = n / 257, f = n % 257;
  const int tid = threadIdx.x, lane = tid & 63, wv = tid >> 6;

  for (int i = tid; i < 128*32; i += 256){
    int r = i >> 5, part = i & 31;
    *(uint4*)(sA + r*264 + part*8) =
        *(const uint4*)(hbuf + ((size_t)n*TT + t0 + r)*HH + part*8);
  }
  for (int i = tid; i < (64*264)/2; i += 256)
    ((unsigned*)sB)[i] = ((const unsigned*)wlin)[i];
  __syncthreads();

  f32x4 acc[2][4];
  #pragma unroll
  for (int m = 0; m < 2; ++m)
    #pragma unroll
    for (int nt = 0; nt < 4; ++nt){
      float bv = blin[nt*16 + (lane & 15)];
      acc[m][nt] = (f32x4){bv, bv, bv, bv};
    }
  const int khi = (lane >> 4) * 8;
  #pragma unroll
  for (int kt = 0; kt < 8; ++kt){
    v8bf av[2];
    #pragma unroll
    for (int m = 0; m < 2; ++m){
      int mt = wv*2 + m;
      av[m] = *(const v8bf*)(sA + (mt*16 + (lane & 15))*264 + kt*32 + khi);
    }
    #pragma unroll
    for (int nt = 0; nt < 4; ++nt){
      v8bf bv = *(const v8bf*)(sB + (nt*16 + (lane & 15))*264 + kt*32 + khi);
      #pragma unroll
      for (int m = 0; m < 2; ++m)
        acc[m][nt] = __builtin_amdgcn_mfma_f32_16x16x32_bf16(av[m], bv, acc[m][nt], 0, 0, 0);
    }
  }
  #pragma unroll
  for (int m = 0; m < 2; ++m){
    int mt = wv*2 + m;
    #pragma unroll
    for (int nt = 0; nt < 4; ++nt){
      int o = nt*16 + (lane & 15);
      int tb = t0 + mt*16 + 4*(lane >> 4);
      *(f32x4*)(out + (((size_t)b*64 + o)*257 + f)*TT + tb) = acc[m][nt];
    }
  }
}

extern "C" void kernel_launch(void* const* d_in, const int* in_sizes, int n_in,
                              void* d_out, int out_size, void* d_ws, size_t ws_size,
                              hipStream_t stream) {
  const float* x   = (const float*)d_in[0];
  const float* Wih = (const float*)d_in[1];
  const float* Whh = (const float*)d_in[2];
  const float* bih = (const float*)d_in[3];
  const float* bhh = (const float*)d_in[4];
  const float* Wl  = (const float*)d_in[5];
  const float* bl  = (const float*)d_in[6];
  float* out = (float*)d_out;

  char* p = (char*)d_ws;
  u16*   wpack = (u16*)p;   p += 655360;                 // 10 slabs
  float* bias  = (float*)p; p += 4096;
  u16*   wlin  = (u16*)p;   p += 33792;
  u16*   ybuf  = (u16*)p;   p += (size_t)NSEQ*TT*CC*2;   // 33.7 MB
  u16*   hbuf  = (u16*)p;                                // 134.7 MB

  hipFuncSetAttribute((const void*)k_lstm,    hipFuncAttributeMaxDynamicSharedMemorySize, LSTM_LDS);
  hipFuncSetAttribute((const void*)k_outproj, hipFuncAttributeMaxDynamicSharedMemorySize, OUTP_LDS);

  k_pack_w <<<1280, 256, 0, stream>>>(Whh, Wih, wpack);
  k_bias   <<<4,    256, 0, stream>>>(bih, bhh, bias);
  k_wlin   <<<66,   256, 0, stream>>>(Wl, wlin);
  k_ytrans <<<1028, 256, 0, stream>>>(x, ybuf);
  k_lstm   <<<65, 512, LSTM_LDS, stream>>>(wpack, bias, ybuf, hbuf);
  k_outproj<<<dim3(1028, 2), 256, OUTP_LDS, stream>>>(hbuf, wlin, bl, out);
}